// Round 15
// baseline (656.928 us; speedup 1.0000x reference)
//
#include <hip/hip_runtime.h>
#include <stdint.h>
#include <cmath>

typedef unsigned short u16;
typedef _Float16 f16;
typedef f16   f16x8 __attribute__((ext_vector_type(8)));
typedef float f32x4 __attribute__((ext_vector_type(4)));
typedef u16   u16x8 __attribute__((ext_vector_type(8)));

#define GLD16(gsrc, ldst)                                                      \
  __builtin_amdgcn_global_load_lds(                                            \
      (__attribute__((address_space(1))) void*)(gsrc),                         \
      (__attribute__((address_space(3))) void*)(ldst), 16, 0, 0)

__device__ __forceinline__ u16 f2h(float x) {
  f16 h = (f16)x;
  return __builtin_bit_cast(u16, h);
}

__device__ __forceinline__ f32x4 mfma16(f16x8 a, f16x8 b, f32x4 c) {
  return __builtin_amdgcn_mfma_f32_16x16x32_f16(a, b, c, 0, 0, 0);
}

// ---------------- segmented f32 -> f16 convert (ONE launch for 5 tensors) ---
__global__ void cvt_multi(const float* __restrict__ s0, u16* __restrict__ d0, long c0,
                          const float* __restrict__ s1, u16* __restrict__ d1, long c1,
                          const float* __restrict__ s2, u16* __restrict__ d2, long c2,
                          const float* __restrict__ s3, u16* __restrict__ d3, long c3,
                          const float* __restrict__ s4, u16* __restrict__ d4, long c4) {
  long i = (long)blockIdx.x * 256 + threadIdx.x;
  const long stride = (long)gridDim.x * 256;
  for (; i < c4; i += stride) {
    const float* s;
    u16* d;
    long base;
    if (i < c0)      { s = s0; d = d0; base = 0;  }
    else if (i < c1) { s = s1; d = d1; base = c0; }
    else if (i < c2) { s = s2; d = d2; base = c1; }
    else if (i < c3) { s = s3; d = d3; base = c2; }
    else             { s = s4; d = d4; base = c3; }
    long j = i - base;
    const float4* p = (const float4*)s + 2 * j;
    float4 a = p[0], b = p[1];
    u16x8 o;
    o[0] = f2h(a.x); o[1] = f2h(a.y); o[2] = f2h(a.z); o[3] = f2h(a.w);
    o[4] = f2h(b.x); o[5] = f2h(b.y); o[6] = f2h(b.z); o[7] = f2h(b.w);
    *((u16x8*)d + j) = o;
  }
}

// ---- shared geometry helper ----
__device__ __forceinline__ void xcd_tile(int& m0, int& n0, int N) {
  int nwg = gridDim.x;
  int orig = blockIdx.x;
  int q8 = nwg >> 3, r8 = nwg & 7;
  int xcd = orig & 7, idx = orig >> 3;
  int wg = (xcd < r8 ? xcd * (q8 + 1) : r8 * (q8 + 1) + (xcd - r8) * q8) + idx;
  const int gn = N >> 8;
  m0 = (wg / gn) * 256;
  n0 = (wg % gn) * 256;
}

// ===== Q-projection GEMM with FUSED f32->f16 A path =========================
// r15: cluster order Q00->Q01->Q10->Q11 with fb0+fb1 loaded up front.
// Each LDS fragment read exactly once (24 ds_read_b128/wave/tile, was 32):
// LDS pipe 320KB -> 256KB per tile, matching gemm_8ph's read volume.
// Peak live regs unchanged (fa 16v + fb0 8v + fb1 8v, same as before).
__global__ __launch_bounds__(512, 2) void gemm_a32(const float* __restrict__ A,
                                                   const u16* __restrict__ B,
                                                   u16* __restrict__ C,
                                                   int M, int N, int K) {
  extern __shared__ char smem[];  // 131072: buf b at b*65536; A @0, B @32768
  const int tid = threadIdx.x;
  const int lane = tid & 63, wid = tid >> 6;
  const int wm = wid >> 2, wn = wid & 3;
  const int lq = lane >> 4, lr = lane & 15;

  int m0, n0;
  xcd_tile(m0, n0, N);
  const int NT = K >> 6;

  const int r0 = tid >> 3;
  const float* pA = A + (size_t)(m0 + r0) * K + (tid & 7) * 8;
  const int dcolA = (((tid & 7) ^ (r0 & 7)) << 4);

  const int kb0 = (((tid & 7) ^ ((tid >> 3) & 7)) << 4);
  const u16* pB = B + (size_t)(n0 + r0) * K + (kb0 >> 1);

#define ALOAD(DST, TT)                                                        \
  do {                                                                        \
    const float* s_ = pA + (size_t)(TT) * 64;                                 \
    _Pragma("unroll") for (int j = 0; j < 4; ++j) {                           \
      DST[2 * j]     = *(const float4*)(s_ + (size_t)(64 * j) * K);           \
      DST[2 * j + 1] = *(const float4*)(s_ + (size_t)(64 * j) * K + 4);       \
    }                                                                         \
  } while (0)

#define AWRITE(SRC, TT)                                                       \
  do {                                                                        \
    char* db_ = smem + ((TT) & 1) * 65536;                                    \
    _Pragma("unroll") for (int j = 0; j < 4; ++j) {                           \
      u16x8 w_;                                                               \
      w_[0] = f2h(SRC[2 * j].x);     w_[1] = f2h(SRC[2 * j].y);               \
      w_[2] = f2h(SRC[2 * j].z);     w_[3] = f2h(SRC[2 * j].w);               \
      w_[4] = f2h(SRC[2 * j + 1].x); w_[5] = f2h(SRC[2 * j + 1].y);           \
      w_[6] = f2h(SRC[2 * j + 1].z); w_[7] = f2h(SRC[2 * j + 1].w);           \
      *(u16x8*)(db_ + (r0 + 64 * j) * 128 + dcolA) = w_;                      \
    }                                                                         \
  } while (0)

#define STAGEB(HALF, TT)                                                      \
  do {                                                                        \
    char* db_ = smem + ((TT) & 1) * 65536 + 32768 + (HALF) * 16384 +          \
                wid * 1024;                                                   \
    const u16* s_ = pB + (size_t)((HALF) * 128) * K + (size_t)(TT) * 64;      \
    GLD16(s_, db_);                                                           \
    GLD16(s_ + (size_t)64 * K, db_ + 8192);                                   \
  } while (0)

  int kx[2];
#pragma unroll
  for (int ks = 0; ks < 2; ++ks)
    kx[ks] = ((ks * 64 + lq * 16) ^ ((lr & 7) << 4));
  const int ABASE = wm * 8192 + lr * 128;
  const int BBASE = 32768 + wn * 4096 + lr * 128;

#define READA(FA, QM)                                                         \
  _Pragma("unroll") for (int m2 = 0; m2 < 4; ++m2)                            \
  _Pragma("unroll") for (int ks = 0; ks < 2; ++ks)                            \
    FA[m2][ks] = *(const f16x8*)(rb + ABASE + (QM) * 16384 + m2 * 2048 + kx[ks]);
#define READB(FB, QN)                                                         \
  _Pragma("unroll") for (int n2 = 0; n2 < 2; ++n2)                            \
  _Pragma("unroll") for (int ks = 0; ks < 2; ++ks)                            \
    FB[n2][ks] = *(const f16x8*)(rb + BBASE + (QN) * 16384 + n2 * 2048 + kx[ks]);
#define CLUSTER(QM, QN, FA, FB)                                               \
  __builtin_amdgcn_s_setprio(1);                                              \
  _Pragma("unroll") for (int m2 = 0; m2 < 4; ++m2)                            \
  _Pragma("unroll") for (int n2 = 0; n2 < 2; ++n2)                            \
  _Pragma("unroll") for (int ks = 0; ks < 2; ++ks)                            \
      acc[QM][QN][m2][n2] =                                                   \
          mfma16(FA[m2][ks], FB[n2][ks], acc[QM][QN][m2][n2]);                \
  __builtin_amdgcn_s_setprio(0);

  f32x4 acc[2][2][4][2] = {};
  float4 a4[8], a4n[8];

  ALOAD(a4, 0);
  STAGEB(0, 0);
  STAGEB(1, 0);
  asm volatile("" ::: "memory");
  AWRITE(a4, 0);
  ALOAD(a4n, 1);
  asm volatile("s_waitcnt vmcnt(8)" ::: "memory");
  asm volatile("s_waitcnt lgkmcnt(0)" ::: "memory");
  __builtin_amdgcn_s_barrier();

  for (int t = 0; t < NT; ++t) {
    const char* rb = smem + (t & 1) * 65536;
    // ---- staging for t+1 issued FIRST: hides under the MFMA clusters ----
    if (t + 1 < NT) {
      STAGEB(0, t + 1);
      STAGEB(1, t + 1);
      asm volatile("" ::: "memory");  // B(t+1) issued before A(t+2) loads
      AWRITE(a4n, t + 1);             // ds_write to buf[(t+1)&1] (safe)
      if (t + 2 < NT) ALOAD(a4n, t + 2);
    }
    // ---- compute on buf[t&1]; each fragment read ONCE (24 reads/wave) ----
    f16x8 fa[4][2], fb0[2][2], fb1[2][2];
    READB(fb0, 0);
    READB(fb1, 1);
    READA(fa, 0);
    CLUSTER(0, 0, fa, fb0);
    CLUSTER(0, 1, fa, fb1);
    READA(fa, 1);
    CLUSTER(1, 0, fa, fb0);
    CLUSTER(1, 1, fa, fb1);
    // ---- boundary: drain STAGEB(t+1) (issued a full MFMA-section ago) ----
    if (t + 1 < NT) {
      if (t + 2 < NT)
        asm volatile("s_waitcnt vmcnt(8)" ::: "memory");  // keep A(t+2) inflight
      else
        asm volatile("s_waitcnt vmcnt(0)" ::: "memory");
      asm volatile("s_waitcnt lgkmcnt(0)" ::: "memory");
      __builtin_amdgcn_s_barrier();
    }
  }
#undef ALOAD
#undef AWRITE
#undef STAGEB
#undef READA
#undef READB
#undef CLUSTER

#pragma unroll
  for (int qm = 0; qm < 2; ++qm)
#pragma unroll
    for (int m2 = 0; m2 < 4; ++m2)
#pragma unroll
      for (int r = 0; r < 4; ++r) {
        int grow = m0 + qm * 128 + wm * 64 + m2 * 16 + lq * 4 + r;
#pragma unroll
        for (int qn = 0; qn < 2; ++qn)
#pragma unroll
          for (int n2 = 0; n2 < 2; ++n2) {
            int gcol = n0 + qn * 128 + wn * 32 + n2 * 16 + lr;
            C[(size_t)grow * N + gcol] = f2h(acc[qm][qn][m2][n2][r]);
          }
      }
}

// ===== 256x256 quadrant-rotation 8-phase GEMM (fa0 held in regs, r12) =======
template <int OUT_F16, int HAS_BIAS>
__global__ __launch_bounds__(512, 2) void gemm_8ph(const u16* __restrict__ A,
                                                   const u16* __restrict__ B,
                                                   void* __restrict__ Cp,
                                                   const float* __restrict__ bias,
                                                   int M, int N, int K) {
  extern __shared__ char smem[];
  const int tid = threadIdx.x;
  const int lane = tid & 63, wid = tid >> 6;
  const int wm = wid >> 2, wn = wid & 3;
  const int lq = lane >> 4, lr = lane & 15;

  int m0, n0;
  xcd_tile(m0, n0, N);
  const int NT = K >> 6;

  const int r0 = tid >> 3;
  const int kb0 = (((tid & 7) ^ ((tid >> 3) & 7)) << 4);
  const u16* pA = A + (size_t)(m0 + r0) * K + (kb0 >> 1);
  const u16* pB = B + (size_t)(n0 + r0) * K + (kb0 >> 1);

#define STAGE(MAT, HALF, TT)                                                  \
  do {                                                                        \
    char* db_ = smem + ((TT) & 1) * 65536 + (MAT) * 32768 +                   \
                (HALF) * 16384 + wid * 1024;                                  \
    const u16* s_ = (MAT ? pB : pA) + (size_t)((HALF) * 128) * K +            \
                    (size_t)(TT) * 64;                                        \
    GLD16(s_, db_);                                                           \
    GLD16(s_ + (size_t)64 * K, db_ + 8192);                                   \
  } while (0)

  int kx[2];
#pragma unroll
  for (int ks = 0; ks < 2; ++ks)
    kx[ks] = ((ks * 64 + lq * 16) ^ ((lr & 7) << 4));
  const int ABASE = wm * 8192 + lr * 128;
  const int BBASE = 32768 + wn * 4096 + lr * 128;

#define READA(FA, QM)                                                         \
  _Pragma("unroll") for (int m2 = 0; m2 < 4; ++m2)                            \
  _Pragma("unroll") for (int ks = 0; ks < 2; ++ks)                            \
    FA[m2][ks] = *(const f16x8*)(rb + ABASE + (QM) * 16384 + m2 * 2048 + kx[ks]);
#define READB(FB, QN)                                                         \
  _Pragma("unroll") for (int n2 = 0; n2 < 2; ++n2)                            \
  _Pragma("unroll") for (int ks = 0; ks < 2; ++ks)                            \
    FB[n2][ks] = *(const f16x8*)(rb + BBASE + (QN) * 16384 + n2 * 2048 + kx[ks]);
#define CLUSTER(QM, QN, FA, FB)                                               \
  __builtin_amdgcn_s_setprio(1);                                              \
  _Pragma("unroll") for (int m2 = 0; m2 < 4; ++m2)                            \
  _Pragma("unroll") for (int n2 = 0; n2 < 2; ++n2)                            \
  _Pragma("unroll") for (int ks = 0; ks < 2; ++ks)                            \
      acc[QM][QN][m2][n2] =                                                   \
          mfma16(FA[m2][ks], FB[n2][ks], acc[QM][QN][m2][n2]);                \
  __builtin_amdgcn_s_setprio(0);

  f32x4 acc[2][2][4][2] = {};

  STAGE(0, 0, 0);
  STAGE(1, 0, 0);
  STAGE(0, 1, 0);
  STAGE(1, 1, 0);
  asm volatile("s_waitcnt vmcnt(0)" ::: "memory");
  __builtin_amdgcn_s_barrier();

  for (int t = 0; t < NT; ++t) {
    const char* rb = smem + (t & 1) * 65536;
    f16x8 fa0[4][2], fa1[4][2], fb0[2][2], fb1[2][2];
    // P0
    READA(fa0, 0);
    READB(fb0, 0);
    if (t + 1 < NT) {
      STAGE(0, 0, t + 1);
      asm volatile("s_waitcnt vmcnt(4)" ::: "memory");
    } else {
      asm volatile("s_waitcnt vmcnt(2)" ::: "memory");
    }
    __builtin_amdgcn_s_barrier();
    asm volatile("s_waitcnt lgkmcnt(0)" ::: "memory");
    CLUSTER(0, 0, fa0, fb0);
    __builtin_amdgcn_s_barrier();
    // P1
    READA(fa1, 1);
    if (t + 1 < NT) {
      STAGE(1, 0, t + 1);
      asm volatile("s_waitcnt vmcnt(4)" ::: "memory");
    } else {
      asm volatile("s_waitcnt vmcnt(0)" ::: "memory");
    }
    __builtin_amdgcn_s_barrier();
    asm volatile("s_waitcnt lgkmcnt(0)" ::: "memory");
    CLUSTER(1, 0, fa1, fb0);
    __builtin_amdgcn_s_barrier();
    // P2
    READB(fb1, 1);
    if (t + 1 < NT) STAGE(0, 1, t + 1);
    __builtin_amdgcn_s_barrier();
    asm volatile("s_waitcnt lgkmcnt(0)" ::: "memory");
    CLUSTER(1, 1, fa1, fb1);
    __builtin_amdgcn_s_barrier();
    // P3 (fa0 held in registers — no re-read)
    if (t + 1 < NT) {
      STAGE(1, 1, t + 1);
      asm volatile("s_waitcnt vmcnt(4)" ::: "memory");
    }
    __builtin_amdgcn_s_barrier();
    asm volatile("s_waitcnt lgkmcnt(0)" ::: "memory");
    CLUSTER(0, 1, fa0, fb1);
    __builtin_amdgcn_s_barrier();
  }
#undef STAGE
#undef READA
#undef READB
#undef CLUSTER

  float bv[2][2];
#pragma unroll
  for (int qn = 0; qn < 2; ++qn)
#pragma unroll
    for (int n2 = 0; n2 < 2; ++n2)
      bv[qn][n2] =
          HAS_BIAS ? bias[n0 + qn * 128 + wn * 32 + n2 * 16 + lr] : 0.0f;
#pragma unroll
  for (int qm = 0; qm < 2; ++qm)
#pragma unroll
    for (int m2 = 0; m2 < 4; ++m2)
#pragma unroll
      for (int r = 0; r < 4; ++r) {
        int grow = m0 + qm * 128 + wm * 64 + m2 * 16 + lq * 4 + r;
#pragma unroll
        for (int qn = 0; qn < 2; ++qn)
#pragma unroll
          for (int n2 = 0; n2 < 2; ++n2) {
            int gcol = n0 + qn * 128 + wn * 32 + n2 * 16 + lr;
            float v = acc[qm][qn][m2][n2][r] + bv[qn][n2];
            if (OUT_F16)
              ((u16*)Cp)[(size_t)grow * N + gcol] = f2h(v);
            else
              ((float*)Cp)[(size_t)grow * N + gcol] = v;
          }
      }
}

// -------- fused K+V projections: ONE launch, grid (20,10) -------------------
__global__ __launch_bounds__(256) void gemm_kv(const u16* __restrict__ A,
                                               const u16* __restrict__ Bk,
                                               const u16* __restrict__ Bv,
                                               u16* __restrict__ Ck,
                                               u16* __restrict__ Cv,
                                               int M, int N, int K) {
  constexpr int BK = 64;
  __shared__ u16 Asm[128 * BK];
  __shared__ u16 Bsm[128 * BK];
  const int tid = threadIdx.x;
  const int lane = tid & 63, wid = tid >> 6;
  const int wm = wid >> 1, wn = wid & 1;
  int nx = blockIdx.x;
  const u16* B;
  u16* C;
  if (nx >= 10) { B = Bv; C = Cv; nx -= 10; }
  else          { B = Bk; C = Ck; }
  const int m0 = blockIdx.y * 128, n0 = nx * 128;
  const int lq = lane >> 4, lr = lane & 15;
  const int koff = lq << 3;

  f32x4 acc[4][4] = {};

  for (int k0 = 0; k0 < K; k0 += BK) {
#pragma unroll
    for (int j = 0; j < 4; ++j) {
      int off = (wid * 4 + j) * 1024 + lane * 16;
      int r = off >> 7;
      int c = (off & 127) >> 1;
      int gr = m0 + r;
      gr = gr < M ? gr : M - 1;
      GLD16(A + (size_t)gr * K + k0 + c, (char*)Asm + (wid * 4 + j) * 1024);
    }
#pragma unroll
    for (int j = 0; j < 4; ++j) {
      int off = (wid * 4 + j) * 1024 + lane * 16;
      int r = off >> 7;
      int c = (off & 127) >> 1;
      GLD16(B + (size_t)(n0 + r) * K + k0 + c, (char*)Bsm + (wid * 4 + j) * 1024);
    }
    __syncthreads();
#pragma unroll
    for (int ks = 0; ks < 2; ++ks) {
      f16x8 af[4], bfr[4];
#pragma unroll
      for (int m = 0; m < 4; ++m)
        af[m] = *(const f16x8*)(Asm + (wm * 64 + m * 16 + lr) * BK + ks * 32 + koff);
#pragma unroll
      for (int n = 0; n < 4; ++n)
        bfr[n] = *(const f16x8*)(Bsm + (wn * 64 + n * 16 + lr) * BK + ks * 32 + koff);
#pragma unroll
      for (int m = 0; m < 4; ++m)
#pragma unroll
        for (int n = 0; n < 4; ++n)
          acc[m][n] = mfma16(af[m], bfr[n], acc[m][n]);
    }
    __syncthreads();
  }

#pragma unroll
  for (int m = 0; m < 4; ++m) {
#pragma unroll
    for (int r = 0; r < 4; ++r) {
      int grow = m0 + wm * 64 + m * 16 + lq * 4 + r;
      if (grow >= M) continue;
#pragma unroll
      for (int n = 0; n < 4; ++n) {
        int gcol = n0 + wn * 64 + n * 16 + lr;
        C[(size_t)grow * N + gcol] = f2h(acc[m][n][r]);
      }
    }
  }
}

// ---------------- fused attention (4 q-tiles/block + coalesced O store) -----
__global__ __launch_bounds__(256) void attn_fused(const u16* __restrict__ Q,
                                                  const u16* __restrict__ Kp,
                                                  const u16* __restrict__ Vp,
                                                  u16* __restrict__ Oa,
                                                  float scale) {
  __shared__ u16 Ksm[80][168];
  __shared__ u16 VT[160][104];
  __shared__ u16 Psm[4][16][96];
  const int tid = threadIdx.x, lane = tid & 63, wid = tid >> 6;
  const int lq = lane >> 4, lr = lane & 15, koff = lq << 3;
  const int qg = blockIdx.x, h = blockIdx.y, b = blockIdx.z;

  {
    u16x8 z = {0, 0, 0, 0, 0, 0, 0, 0};
    for (int i = tid; i < 80 * 168 / 8; i += 256) ((u16x8*)&Ksm[0][0])[i] = z;
    for (int i = tid; i < 160 * 104 / 8; i += 256) ((u16x8*)&VT[0][0])[i] = z;
    for (int i = tid; i < 4 * 16 * 96 / 8; i += 256) ((u16x8*)&Psm[0][0][0])[i] = z;
  }
  __syncthreads();

  const size_t kvbase = ((size_t)b * 77) * 1280 + (size_t)h * 160;
  for (int i = tid; i < 77 * 20; i += 256) {
    int r = i / 20, c8 = (i % 20) * 8;
    *(u16x8*)&Ksm[r][c8] = *(const u16x8*)(Kp + kvbase + (size_t)r * 1280 + c8);
  }
  for (int i = tid; i < 77 * 20; i += 256) {
    int r = i / 20, c8 = (i % 20) * 8;
    u16x8 v = *(const u16x8*)(Vp + kvbase + (size_t)r * 1280 + c8);
#pragma unroll
    for (int j = 0; j < 8; ++j) VT[c8 + j][r] = v[j];
  }
  __syncthreads();

  for (int it = 0; it < 4; ++it) {
    const int qt = qg * 4 + it;

    f16x8 qf[5];
    const int qrow = qt * 64 + wid * 16 + lr;
    const size_t qbase = ((size_t)b * 4096 + qrow) * 1280 + (size_t)h * 160;
#pragma unroll
    for (int ks = 0; ks < 5; ++ks)
      qf[ks] = *(const f16x8*)(Q + qbase + ks * 32 + koff);

    f32x4 sc[5];
#pragma unroll
    for (int nt = 0; nt < 5; ++nt) {
      sc[nt] = (f32x4){0.f, 0.f, 0.f, 0.f};
#pragma unroll
      for (int ks = 0; ks < 5; ++ks) {
        f16x8 kf = *(const f16x8*)&Ksm[nt * 16 + lr][ks * 32 + koff];
        sc[nt] = mfma16(qf[ks], kf, sc[nt]);
      }
    }

    float p[5][4];
#pragma unroll
    for (int r = 0; r < 4; ++r) {
      float mx = -1e30f;
#pragma unroll
      for (int nt = 0; nt < 5; ++nt) {
        float v = sc[nt][r] * scale;
        if (nt * 16 + lr >= 77) v = -1e30f;
        p[nt][r] = v;
        mx = fmaxf(mx, v);
      }
#pragma unroll
      for (int d = 1; d < 16; d <<= 1) mx = fmaxf(mx, __shfl_xor(mx, d));
      float sum = 0.f;
#pragma unroll
      for (int nt = 0; nt < 5; ++nt) {
        float e = __expf(p[nt][r] - mx);
        p[nt][r] = e;
        sum += e;
      }
#pragma unroll
      for (int d = 1; d < 16; d <<= 1) sum += __shfl_xor(sum, d);
      float inv = 1.f / sum;
#pragma unroll
      for (int nt = 0; nt < 5; ++nt) p[nt][r] *= inv;
    }

#pragma unroll
    for (int r = 0; r < 4; ++r)
#pragma unroll
      for (int nt = 0; nt < 5; ++nt)
        Psm[wid][lq * 4 + r][nt * 16 + lr] = f2h(p[nt][r]);

    f32x4 ov[10];
#pragma unroll
    for (int n2 = 0; n2 < 10; ++n2) ov[n2] = (f32x4){0.f, 0.f, 0.f, 0.f};
#pragma unroll
    for (int k2 = 0; k2 < 3; ++k2) {
      f16x8 pf = *(const f16x8*)&Psm[wid][lr][k2 * 32 + koff];
#pragma unroll
      for (int n2 = 0; n2 < 10; ++n2) {
        f16x8 vf = *(const f16x8*)&VT[n2 * 16 + lr][k2 * 32 + koff];
        ov[n2] = mfma16(pf, vf, ov[n2]);
      }
    }

    const size_t ob = ((size_t)b * 4096 + (size_t)qt * 64 + wid * 16) * 1280 +
                      (size_t)h * 160;
#pragma unroll
    for (int c = 0; c < 2; ++c) {
#pragma unroll
      for (int r = 0; r < 4; ++r)
#pragma unroll
        for (int n2l = 0; n2l < 5; ++n2l)
          Psm[wid][lq * 4 + r][n2l * 16 + lr] = f2h(ov[c * 5 + n2l][r]);
#pragma unroll
      for (int u0 = 0; u0 < 3; ++u0) {
        int u = lane + u0 * 64;
        if (u < 160) {
          int rr = u / 10, cc = u - rr * 10;
          u16x8 v = *(const u16x8*)&Psm[wid][rr][cc * 8];
          *(u16x8*)(Oa + ob + (size_t)rr * 1280 + c * 80 + cc * 8) = v;
        }
      }
    }
  }
}

// ---------------- host orchestration ----------------------------------------
extern "C" void kernel_launch(void* const* d_in, const int* in_sizes, int n_in,
                              void* d_out, int out_size, void* d_ws,
                              size_t ws_size, hipStream_t stream) {
  (void)in_sizes; (void)n_in; (void)out_size; (void)ws_size;
  const float* hs  = (const float*)d_in[0];
  const float* enc = (const float*)d_in[1];
  const float* Wq  = (const float*)d_in[2];
  const float* Wk  = (const float*)d_in[3];
  const float* Wv  = (const float*)d_in[4];
  const float* Wo  = (const float*)d_in[5];
  const float* bo  = (const float*)d_in[6];
  float* out = (float*)d_out;

  const int B = 16, S = 4096, SKV = 77, HID = 1280, CDIM = 768;
  const int MQ = B * S;
  const int MKV = B * SKV;

  char* ws = (char*)d_ws;
  size_t off = 0;
  auto alloc = [&](size_t bytes) -> char* {
    char* p = ws + off;
    off += (bytes + 255) & ~(size_t)255;
    return p;
  };
  u16* q_h    = (u16*)alloc((size_t)MQ * HID * 2);
  u16* attn_h = (u16*)alloc((size_t)MQ * HID * 2);
  u16* enc_h  = (u16*)alloc((size_t)MKV * CDIM * 2);
  u16* wq_h   = (u16*)alloc((size_t)HID * HID * 2);
  u16* wk_h   = (u16*)alloc((size_t)HID * CDIM * 2);
  u16* wv_h   = (u16*)alloc((size_t)HID * CDIM * 2);
  u16* wo_h   = (u16*)alloc((size_t)HID * HID * 2);
  u16* k_h    = (u16*)alloc((size_t)MKV * HID * 2);
  u16* v_h    = (u16*)alloc((size_t)MKV * HID * 2);

  // ---- one segmented convert for all 5 small tensors ----
  const long n8_enc = (long)MKV * CDIM / 8;
  const long n8_wq  = (long)HID * HID / 8;
  const long n8_wk  = (long)HID * CDIM / 8;
  const long c0 = n8_enc;
  const long c1 = c0 + n8_wq;
  const long c2 = c1 + n8_wk;
  const long c3 = c2 + n8_wk;
  const long c4 = c3 + n8_wq;
  cvt_multi<<<2048, 256, 0, stream>>>(enc, enc_h, c0, Wq, wq_h, c1,
                                      Wk, wk_h, c2, Wv, wv_h, c3,
                                      Wo, wo_h, c4);

  // ---- K and V projections in one launch ----
  gemm_kv<<<dim3(20, 10), 256, 0, stream>>>(enc_h, wk_h, wv_h, k_h, v_h,
                                            MKV, HID, CDIM);

  // ---- Q projection with fused f32->f16 A path ----
  const int grid_big = (MQ / 256) * (HID / 256);
  gemm_a32<<<dim3(grid_big), dim3(512), 131072, stream>>>(
      hs, wq_h, q_h, MQ, HID, HID);

  const float scale = 1.0f / sqrtf(160.0f);
  attn_fused<<<dim3(16, 8, 16), 256, 0, stream>>>(q_h, k_h, v_h, attn_h, scale);

  // ---- output projection (+bias, f32 out) ----
  gemm_8ph<0, 1><<<dim3(grid_big), dim3(512), 131072, stream>>>(
      attn_h, wo_h, out, bo, MQ, HID, HID);
}

// Round 16
// 645.192 us; speedup vs baseline: 1.0182x; 1.0182x over previous
//
#include <hip/hip_runtime.h>
#include <stdint.h>
#include <cmath>

typedef unsigned short u16;
typedef _Float16 f16;
typedef f16   f16x8 __attribute__((ext_vector_type(8)));
typedef float f32x4 __attribute__((ext_vector_type(4)));
typedef u16   u16x8 __attribute__((ext_vector_type(8)));

#define GLD16(gsrc, ldst)                                                      \
  __builtin_amdgcn_global_load_lds(                                            \
      (__attribute__((address_space(1))) void*)(gsrc),                         \
      (__attribute__((address_space(3))) void*)(ldst), 16, 0, 0)

__device__ __forceinline__ u16 f2h(float x) {
  f16 h = (f16)x;
  return __builtin_bit_cast(u16, h);
}

__device__ __forceinline__ f32x4 mfma16(f16x8 a, f16x8 b, f32x4 c) {
  return __builtin_amdgcn_mfma_f32_16x16x32_f16(a, b, c, 0, 0, 0);
}

// ---------------- segmented f32 -> f16 convert (ONE launch for 5 tensors) ---
__global__ void cvt_multi(const float* __restrict__ s0, u16* __restrict__ d0, long c0,
                          const float* __restrict__ s1, u16* __restrict__ d1, long c1,
                          const float* __restrict__ s2, u16* __restrict__ d2, long c2,
                          const float* __restrict__ s3, u16* __restrict__ d3, long c3,
                          const float* __restrict__ s4, u16* __restrict__ d4, long c4) {
  long i = (long)blockIdx.x * 256 + threadIdx.x;
  const long stride = (long)gridDim.x * 256;
  for (; i < c4; i += stride) {
    const float* s;
    u16* d;
    long base;
    if (i < c0)      { s = s0; d = d0; base = 0;  }
    else if (i < c1) { s = s1; d = d1; base = c0; }
    else if (i < c2) { s = s2; d = d2; base = c1; }
    else if (i < c3) { s = s3; d = d3; base = c2; }
    else             { s = s4; d = d4; base = c3; }
    long j = i - base;
    const float4* p = (const float4*)s + 2 * j;
    float4 a = p[0], b = p[1];
    u16x8 o;
    o[0] = f2h(a.x); o[1] = f2h(a.y); o[2] = f2h(a.z); o[3] = f2h(a.w);
    o[4] = f2h(b.x); o[5] = f2h(b.y); o[6] = f2h(b.z); o[7] = f2h(b.w);
    *((u16x8*)d + j) = o;
  }
}

// ---- shared geometry helper ----
__device__ __forceinline__ void xcd_tile(int& m0, int& n0, int N) {
  int nwg = gridDim.x;
  int orig = blockIdx.x;
  int q8 = nwg >> 3, r8 = nwg & 7;
  int xcd = orig & 7, idx = orig >> 3;
  int wg = (xcd < r8 ? xcd * (q8 + 1) : r8 * (q8 + 1) + (xcd - r8) * q8) + idx;
  const int gn = N >> 8;
  m0 = (wg / gn) * 256;
  n0 = (wg % gn) * 256;
}

// ===== Q-projection GEMM with FUSED f32->f16 A path (r15, unchanged) ========
__global__ __launch_bounds__(512, 2) void gemm_a32(const float* __restrict__ A,
                                                   const u16* __restrict__ B,
                                                   u16* __restrict__ C,
                                                   int M, int N, int K) {
  extern __shared__ char smem[];  // 131072: buf b at b*65536; A @0, B @32768
  const int tid = threadIdx.x;
  const int lane = tid & 63, wid = tid >> 6;
  const int wm = wid >> 2, wn = wid & 3;
  const int lq = lane >> 4, lr = lane & 15;

  int m0, n0;
  xcd_tile(m0, n0, N);
  const int NT = K >> 6;

  const int r0 = tid >> 3;
  const float* pA = A + (size_t)(m0 + r0) * K + (tid & 7) * 8;
  const int dcolA = (((tid & 7) ^ (r0 & 7)) << 4);

  const int kb0 = (((tid & 7) ^ ((tid >> 3) & 7)) << 4);
  const u16* pB = B + (size_t)(n0 + r0) * K + (kb0 >> 1);

#define ALOAD(DST, TT)                                                        \
  do {                                                                        \
    const float* s_ = pA + (size_t)(TT) * 64;                                 \
    _Pragma("unroll") for (int j = 0; j < 4; ++j) {                           \
      DST[2 * j]     = *(const float4*)(s_ + (size_t)(64 * j) * K);           \
      DST[2 * j + 1] = *(const float4*)(s_ + (size_t)(64 * j) * K + 4);       \
    }                                                                         \
  } while (0)

#define AWRITE(SRC, TT)                                                       \
  do {                                                                        \
    char* db_ = smem + ((TT) & 1) * 65536;                                    \
    _Pragma("unroll") for (int j = 0; j < 4; ++j) {                           \
      u16x8 w_;                                                               \
      w_[0] = f2h(SRC[2 * j].x);     w_[1] = f2h(SRC[2 * j].y);               \
      w_[2] = f2h(SRC[2 * j].z);     w_[3] = f2h(SRC[2 * j].w);               \
      w_[4] = f2h(SRC[2 * j + 1].x); w_[5] = f2h(SRC[2 * j + 1].y);           \
      w_[6] = f2h(SRC[2 * j + 1].z); w_[7] = f2h(SRC[2 * j + 1].w);           \
      *(u16x8*)(db_ + (r0 + 64 * j) * 128 + dcolA) = w_;                      \
    }                                                                         \
  } while (0)

#define STAGEB(HALF, TT)                                                      \
  do {                                                                        \
    char* db_ = smem + ((TT) & 1) * 65536 + 32768 + (HALF) * 16384 +          \
                wid * 1024;                                                   \
    const u16* s_ = pB + (size_t)((HALF) * 128) * K + (size_t)(TT) * 64;      \
    GLD16(s_, db_);                                                           \
    GLD16(s_ + (size_t)64 * K, db_ + 8192);                                   \
  } while (0)

  int kx[2];
#pragma unroll
  for (int ks = 0; ks < 2; ++ks)
    kx[ks] = ((ks * 64 + lq * 16) ^ ((lr & 7) << 4));
  const int ABASE = wm * 8192 + lr * 128;
  const int BBASE = 32768 + wn * 4096 + lr * 128;

#define READA(FA, QM)                                                         \
  _Pragma("unroll") for (int m2 = 0; m2 < 4; ++m2)                            \
  _Pragma("unroll") for (int ks = 0; ks < 2; ++ks)                            \
    FA[m2][ks] = *(const f16x8*)(rb + ABASE + (QM) * 16384 + m2 * 2048 + kx[ks]);
#define READB(FB, QN)                                                         \
  _Pragma("unroll") for (int n2 = 0; n2 < 2; ++n2)                            \
  _Pragma("unroll") for (int ks = 0; ks < 2; ++ks)                            \
    FB[n2][ks] = *(const f16x8*)(rb + BBASE + (QN) * 16384 + n2 * 2048 + kx[ks]);
#define CLUSTER(QM, QN, FA, FB)                                               \
  __builtin_amdgcn_s_setprio(1);                                              \
  _Pragma("unroll") for (int m2 = 0; m2 < 4; ++m2)                            \
  _Pragma("unroll") for (int n2 = 0; n2 < 2; ++n2)                            \
  _Pragma("unroll") for (int ks = 0; ks < 2; ++ks)                            \
      acc[QM][QN][m2][n2] =                                                   \
          mfma16(FA[m2][ks], FB[n2][ks], acc[QM][QN][m2][n2]);                \
  __builtin_amdgcn_s_setprio(0);

  f32x4 acc[2][2][4][2] = {};
  float4 a4[8], a4n[8];

  ALOAD(a4, 0);
  STAGEB(0, 0);
  STAGEB(1, 0);
  asm volatile("" ::: "memory");
  AWRITE(a4, 0);
  ALOAD(a4n, 1);
  asm volatile("s_waitcnt vmcnt(8)" ::: "memory");
  asm volatile("s_waitcnt lgkmcnt(0)" ::: "memory");
  __builtin_amdgcn_s_barrier();

  for (int t = 0; t < NT; ++t) {
    const char* rb = smem + (t & 1) * 65536;
    if (t + 1 < NT) {
      STAGEB(0, t + 1);
      STAGEB(1, t + 1);
      asm volatile("" ::: "memory");
      AWRITE(a4n, t + 1);
      if (t + 2 < NT) ALOAD(a4n, t + 2);
    }
    f16x8 fa[4][2], fb0[2][2], fb1[2][2];
    READB(fb0, 0);
    READB(fb1, 1);
    READA(fa, 0);
    CLUSTER(0, 0, fa, fb0);
    CLUSTER(0, 1, fa, fb1);
    READA(fa, 1);
    CLUSTER(1, 0, fa, fb0);
    CLUSTER(1, 1, fa, fb1);
    if (t + 1 < NT) {
      if (t + 2 < NT)
        asm volatile("s_waitcnt vmcnt(8)" ::: "memory");
      else
        asm volatile("s_waitcnt vmcnt(0)" ::: "memory");
      asm volatile("s_waitcnt lgkmcnt(0)" ::: "memory");
      __builtin_amdgcn_s_barrier();
    }
  }
#undef ALOAD
#undef AWRITE
#undef STAGEB
#undef READA
#undef READB
#undef CLUSTER

#pragma unroll
  for (int qm = 0; qm < 2; ++qm)
#pragma unroll
    for (int m2 = 0; m2 < 4; ++m2)
#pragma unroll
      for (int r = 0; r < 4; ++r) {
        int grow = m0 + qm * 128 + wm * 64 + m2 * 16 + lq * 4 + r;
#pragma unroll
        for (int qn = 0; qn < 2; ++qn)
#pragma unroll
          for (int n2 = 0; n2 < 2; ++n2) {
            int gcol = n0 + qn * 128 + wn * 32 + n2 * 16 + lr;
            C[(size_t)grow * N + gcol] = f2h(acc[qm][qn][m2][n2][r]);
          }
      }
}

// ===== 256x256 GEMM, r16: 2-barrier / 2-counted-vmcnt per K-tile ============
// Invariant entering tile t: A0,B0(t) landed+published; A1,B1(t) in flight.
// Top: read fa0/fb0, stage A0B0(t+1) [outstanding 8] -> vmcnt(4) retires
// A1B1(t) -> barrier -> 16 MFMA; read fa1/fb1; 16 MFMA; stage A1B1(t+1);
// 32 MFMA (fa0 held) -> vmcnt(4) retires A0B0(t+1) -> barrier.
template <int OUT_F16, int HAS_BIAS>
__global__ __launch_bounds__(512, 2) void gemm_8ph(const u16* __restrict__ A,
                                                   const u16* __restrict__ B,
                                                   void* __restrict__ Cp,
                                                   const float* __restrict__ bias,
                                                   int M, int N, int K) {
  extern __shared__ char smem[];
  const int tid = threadIdx.x;
  const int lane = tid & 63, wid = tid >> 6;
  const int wm = wid >> 2, wn = wid & 3;
  const int lq = lane >> 4, lr = lane & 15;

  int m0, n0;
  xcd_tile(m0, n0, N);
  const int NT = K >> 6;

  const int r0 = tid >> 3;
  const int kb0 = (((tid & 7) ^ ((tid >> 3) & 7)) << 4);
  const u16* pA = A + (size_t)(m0 + r0) * K + (kb0 >> 1);
  const u16* pB = B + (size_t)(n0 + r0) * K + (kb0 >> 1);

#define STAGE(MAT, HALF, TT)                                                  \
  do {                                                                        \
    char* db_ = smem + ((TT) & 1) * 65536 + (MAT) * 32768 +                   \
                (HALF) * 16384 + wid * 1024;                                  \
    const u16* s_ = (MAT ? pB : pA) + (size_t)((HALF) * 128) * K +            \
                    (size_t)(TT) * 64;                                        \
    GLD16(s_, db_);                                                           \
    GLD16(s_ + (size_t)64 * K, db_ + 8192);                                   \
  } while (0)

  int kx[2];
#pragma unroll
  for (int ks = 0; ks < 2; ++ks)
    kx[ks] = ((ks * 64 + lq * 16) ^ ((lr & 7) << 4));
  const int ABASE = wm * 8192 + lr * 128;
  const int BBASE = 32768 + wn * 4096 + lr * 128;

#define READA(FA, QM)                                                         \
  _Pragma("unroll") for (int m2 = 0; m2 < 4; ++m2)                            \
  _Pragma("unroll") for (int ks = 0; ks < 2; ++ks)                            \
    FA[m2][ks] = *(const f16x8*)(rb + ABASE + (QM) * 16384 + m2 * 2048 + kx[ks]);
#define READB(FB, QN)                                                         \
  _Pragma("unroll") for (int n2 = 0; n2 < 2; ++n2)                            \
  _Pragma("unroll") for (int ks = 0; ks < 2; ++ks)                            \
    FB[n2][ks] = *(const f16x8*)(rb + BBASE + (QN) * 16384 + n2 * 2048 + kx[ks]);
#define CLUSTER(QM, QN, FA, FB)                                               \
  __builtin_amdgcn_s_setprio(1);                                              \
  _Pragma("unroll") for (int m2 = 0; m2 < 4; ++m2)                            \
  _Pragma("unroll") for (int n2 = 0; n2 < 2; ++n2)                            \
  _Pragma("unroll") for (int ks = 0; ks < 2; ++ks)                            \
      acc[QM][QN][m2][n2] =                                                   \
          mfma16(FA[m2][ks], FB[n2][ks], acc[QM][QN][m2][n2]);                \
  __builtin_amdgcn_s_setprio(0);

  f32x4 acc[2][2][4][2] = {};

  // prologue: full tile-0 stage; wait for A0,B0(0) only (A1,B1 stay in flight)
  STAGE(0, 0, 0);
  STAGE(1, 0, 0);
  STAGE(0, 1, 0);
  STAGE(1, 1, 0);
  asm volatile("s_waitcnt vmcnt(4)" ::: "memory");
  __builtin_amdgcn_s_barrier();

  for (int t = 0; t < NT; ++t) {
    const char* rb = smem + (t & 1) * 65536;
    f16x8 fa0[4][2], fa1[4][2], fb0[2][2], fb1[2][2];
    // ---- top: fragments of half-0; stage A0,B0(t+1) ----
    READA(fa0, 0);
    READB(fb0, 0);
    if (t + 1 < NT) {
      STAGE(0, 0, t + 1);
      STAGE(1, 0, t + 1);
      asm volatile("s_waitcnt vmcnt(4)" ::: "memory");  // A1,B1(t) landed
    } else {
      asm volatile("s_waitcnt vmcnt(0)" ::: "memory");  // drain last tile
    }
    __builtin_amdgcn_s_barrier();  // publish A1,B1(t)
    CLUSTER(0, 0, fa0, fb0);
    // ---- half-1 fragments (published above) ----
    READA(fa1, 1);
    READB(fb1, 1);
    CLUSTER(1, 0, fa1, fb0);
    if (t + 1 < NT) {
      STAGE(0, 1, t + 1);
      STAGE(1, 1, t + 1);
    }
    CLUSTER(1, 1, fa1, fb1);
    CLUSTER(0, 1, fa0, fb1);  // fa0 held in registers
    // ---- boundary: A0,B0(t+1) landed; A1,B1(t+1) stay in flight ----
    if (t + 1 < NT) {
      asm volatile("s_waitcnt vmcnt(4)" ::: "memory");
      __builtin_amdgcn_s_barrier();
    }
  }
#undef STAGE
#undef READA
#undef READB
#undef CLUSTER

  float bv[2][2];
#pragma unroll
  for (int qn = 0; qn < 2; ++qn)
#pragma unroll
    for (int n2 = 0; n2 < 2; ++n2)
      bv[qn][n2] =
          HAS_BIAS ? bias[n0 + qn * 128 + wn * 32 + n2 * 16 + lr] : 0.0f;
#pragma unroll
  for (int qm = 0; qm < 2; ++qm)
#pragma unroll
    for (int m2 = 0; m2 < 4; ++m2)
#pragma unroll
      for (int r = 0; r < 4; ++r) {
        int grow = m0 + qm * 128 + wm * 64 + m2 * 16 + lq * 4 + r;
#pragma unroll
        for (int qn = 0; qn < 2; ++qn)
#pragma unroll
          for (int n2 = 0; n2 < 2; ++n2) {
            int gcol = n0 + qn * 128 + wn * 32 + n2 * 16 + lr;
            float v = acc[qm][qn][m2][n2][r] + bv[qn][n2];
            if (OUT_F16)
              ((u16*)Cp)[(size_t)grow * N + gcol] = f2h(v);
            else
              ((float*)Cp)[(size_t)grow * N + gcol] = v;
          }
      }
}

// -------- fused K+V projections: ONE launch, grid (20,10) -------------------
__global__ __launch_bounds__(256) void gemm_kv(const u16* __restrict__ A,
                                               const u16* __restrict__ Bk,
                                               const u16* __restrict__ Bv,
                                               u16* __restrict__ Ck,
                                               u16* __restrict__ Cv,
                                               int M, int N, int K) {
  constexpr int BK = 64;
  __shared__ u16 Asm[128 * BK];
  __shared__ u16 Bsm[128 * BK];
  const int tid = threadIdx.x;
  const int lane = tid & 63, wid = tid >> 6;
  const int wm = wid >> 1, wn = wid & 1;
  int nx = blockIdx.x;
  const u16* B;
  u16* C;
  if (nx >= 10) { B = Bv; C = Cv; nx -= 10; }
  else          { B = Bk; C = Ck; }
  const int m0 = blockIdx.y * 128, n0 = nx * 128;
  const int lq = lane >> 4, lr = lane & 15;
  const int koff = lq << 3;

  f32x4 acc[4][4] = {};

  for (int k0 = 0; k0 < K; k0 += BK) {
#pragma unroll
    for (int j = 0; j < 4; ++j) {
      int off = (wid * 4 + j) * 1024 + lane * 16;
      int r = off >> 7;
      int c = (off & 127) >> 1;
      int gr = m0 + r;
      gr = gr < M ? gr : M - 1;
      GLD16(A + (size_t)gr * K + k0 + c, (char*)Asm + (wid * 4 + j) * 1024);
    }
#pragma unroll
    for (int j = 0; j < 4; ++j) {
      int off = (wid * 4 + j) * 1024 + lane * 16;
      int r = off >> 7;
      int c = (off & 127) >> 1;
      GLD16(B + (size_t)(n0 + r) * K + k0 + c, (char*)Bsm + (wid * 4 + j) * 1024);
    }
    __syncthreads();
#pragma unroll
    for (int ks = 0; ks < 2; ++ks) {
      f16x8 af[4], bfr[4];
#pragma unroll
      for (int m = 0; m < 4; ++m)
        af[m] = *(const f16x8*)(Asm + (wm * 64 + m * 16 + lr) * BK + ks * 32 + koff);
#pragma unroll
      for (int n = 0; n < 4; ++n)
        bfr[n] = *(const f16x8*)(Bsm + (wn * 64 + n * 16 + lr) * BK + ks * 32 + koff);
#pragma unroll
      for (int m = 0; m < 4; ++m)
#pragma unroll
        for (int n = 0; n < 4; ++n)
          acc[m][n] = mfma16(af[m], bfr[n], acc[m][n]);
    }
    __syncthreads();
  }

#pragma unroll
  for (int m = 0; m < 4; ++m) {
#pragma unroll
    for (int r = 0; r < 4; ++r) {
      int grow = m0 + wm * 64 + m * 16 + lq * 4 + r;
      if (grow >= M) continue;
#pragma unroll
      for (int n = 0; n < 4; ++n) {
        int gcol = n0 + wn * 64 + n * 16 + lr;
        C[(size_t)grow * N + gcol] = f2h(acc[m][n][r]);
      }
    }
  }
}

// ---------------- fused attention (4 q-tiles/block + coalesced O store) -----
__global__ __launch_bounds__(256) void attn_fused(const u16* __restrict__ Q,
                                                  const u16* __restrict__ Kp,
                                                  const u16* __restrict__ Vp,
                                                  u16* __restrict__ Oa,
                                                  float scale) {
  __shared__ u16 Ksm[80][168];
  __shared__ u16 VT[160][104];
  __shared__ u16 Psm[4][16][96];
  const int tid = threadIdx.x, lane = tid & 63, wid = tid >> 6;
  const int lq = lane >> 4, lr = lane & 15, koff = lq << 3;
  const int qg = blockIdx.x, h = blockIdx.y, b = blockIdx.z;

  {
    u16x8 z = {0, 0, 0, 0, 0, 0, 0, 0};
    for (int i = tid; i < 80 * 168 / 8; i += 256) ((u16x8*)&Ksm[0][0])[i] = z;
    for (int i = tid; i < 160 * 104 / 8; i += 256) ((u16x8*)&VT[0][0])[i] = z;
    for (int i = tid; i < 4 * 16 * 96 / 8; i += 256) ((u16x8*)&Psm[0][0][0])[i] = z;
  }
  __syncthreads();

  const size_t kvbase = ((size_t)b * 77) * 1280 + (size_t)h * 160;
  for (int i = tid; i < 77 * 20; i += 256) {
    int r = i / 20, c8 = (i % 20) * 8;
    *(u16x8*)&Ksm[r][c8] = *(const u16x8*)(Kp + kvbase + (size_t)r * 1280 + c8);
  }
  for (int i = tid; i < 77 * 20; i += 256) {
    int r = i / 20, c8 = (i % 20) * 8;
    u16x8 v = *(const u16x8*)(Vp + kvbase + (size_t)r * 1280 + c8);
#pragma unroll
    for (int j = 0; j < 8; ++j) VT[c8 + j][r] = v[j];
  }
  __syncthreads();

  for (int it = 0; it < 4; ++it) {
    const int qt = qg * 4 + it;

    f16x8 qf[5];
    const int qrow = qt * 64 + wid * 16 + lr;
    const size_t qbase = ((size_t)b * 4096 + qrow) * 1280 + (size_t)h * 160;
#pragma unroll
    for (int ks = 0; ks < 5; ++ks)
      qf[ks] = *(const f16x8*)(Q + qbase + ks * 32 + koff);

    f32x4 sc[5];
#pragma unroll
    for (int nt = 0; nt < 5; ++nt) {
      sc[nt] = (f32x4){0.f, 0.f, 0.f, 0.f};
#pragma unroll
      for (int ks = 0; ks < 5; ++ks) {
        f16x8 kf = *(const f16x8*)&Ksm[nt * 16 + lr][ks * 32 + koff];
        sc[nt] = mfma16(qf[ks], kf, sc[nt]);
      }
    }

    float p[5][4];
#pragma unroll
    for (int r = 0; r < 4; ++r) {
      float mx = -1e30f;
#pragma unroll
      for (int nt = 0; nt < 5; ++nt) {
        float v = sc[nt][r] * scale;
        if (nt * 16 + lr >= 77) v = -1e30f;
        p[nt][r] = v;
        mx = fmaxf(mx, v);
      }
#pragma unroll
      for (int d = 1; d < 16; d <<= 1) mx = fmaxf(mx, __shfl_xor(mx, d));
      float sum = 0.f;
#pragma unroll
      for (int nt = 0; nt < 5; ++nt) {
        float e = __expf(p[nt][r] - mx);
        p[nt][r] = e;
        sum += e;
      }
#pragma unroll
      for (int d = 1; d < 16; d <<= 1) sum += __shfl_xor(sum, d);
      float inv = 1.f / sum;
#pragma unroll
      for (int nt = 0; nt < 5; ++nt) p[nt][r] *= inv;
    }

#pragma unroll
    for (int r = 0; r < 4; ++r)
#pragma unroll
      for (int nt = 0; nt < 5; ++nt)
        Psm[wid][lq * 4 + r][nt * 16 + lr] = f2h(p[nt][r]);

    f32x4 ov[10];
#pragma unroll
    for (int n2 = 0; n2 < 10; ++n2) ov[n2] = (f32x4){0.f, 0.f, 0.f, 0.f};
#pragma unroll
    for (int k2 = 0; k2 < 3; ++k2) {
      f16x8 pf = *(const f16x8*)&Psm[wid][lr][k2 * 32 + koff];
#pragma unroll
      for (int n2 = 0; n2 < 10; ++n2) {
        f16x8 vf = *(const f16x8*)&VT[n2 * 16 + lr][k2 * 32 + koff];
        ov[n2] = mfma16(pf, vf, ov[n2]);
      }
    }

    const size_t ob = ((size_t)b * 4096 + (size_t)qt * 64 + wid * 16) * 1280 +
                      (size_t)h * 160;
#pragma unroll
    for (int c = 0; c < 2; ++c) {
#pragma unroll
      for (int r = 0; r < 4; ++r)
#pragma unroll
        for (int n2l = 0; n2l < 5; ++n2l)
          Psm[wid][lq * 4 + r][n2l * 16 + lr] = f2h(ov[c * 5 + n2l][r]);
#pragma unroll
      for (int u0 = 0; u0 < 3; ++u0) {
        int u = lane + u0 * 64;
        if (u < 160) {
          int rr = u / 10, cc = u - rr * 10;
          u16x8 v = *(const u16x8*)&Psm[wid][rr][cc * 8];
          *(u16x8*)(Oa + ob + (size_t)rr * 1280 + c * 80 + cc * 8) = v;
        }
      }
    }
  }
}

// ---------------- host orchestration ----------------------------------------
extern "C" void kernel_launch(void* const* d_in, const int* in_sizes, int n_in,
                              void* d_out, int out_size, void* d_ws,
                              size_t ws_size, hipStream_t stream) {
  (void)in_sizes; (void)n_in; (void)out_size; (void)ws_size;
  const float* hs  = (const float*)d_in[0];
  const float* enc = (const float*)d_in[1];
  const float* Wq  = (const float*)d_in[2];
  const float* Wk  = (const float*)d_in[3];
  const float* Wv  = (const float*)d_in[4];
  const float* Wo  = (const float*)d_in[5];
  const float* bo  = (const float*)d_in[6];
  float* out = (float*)d_out;

  const int B = 16, S = 4096, SKV = 77, HID = 1280, CDIM = 768;
  const int MQ = B * S;
  const int MKV = B * SKV;

  char* ws = (char*)d_ws;
  size_t off = 0;
  auto alloc = [&](size_t bytes) -> char* {
    char* p = ws + off;
    off += (bytes + 255) & ~(size_t)255;
    return p;
  };
  u16* q_h    = (u16*)alloc((size_t)MQ * HID * 2);
  u16* attn_h = (u16*)alloc((size_t)MQ * HID * 2);
  u16* enc_h  = (u16*)alloc((size_t)MKV * CDIM * 2);
  u16* wq_h   = (u16*)alloc((size_t)HID * HID * 2);
  u16* wk_h   = (u16*)alloc((size_t)HID * CDIM * 2);
  u16* wv_h   = (u16*)alloc((size_t)HID * CDIM * 2);
  u16* wo_h   = (u16*)alloc((size_t)HID * HID * 2);
  u16* k_h    = (u16*)alloc((size_t)MKV * HID * 2);
  u16* v_h    = (u16*)alloc((size_t)MKV * HID * 2);

  // ---- one segmented convert for all 5 small tensors ----
  const long n8_enc = (long)MKV * CDIM / 8;
  const long n8_wq  = (long)HID * HID / 8;
  const long n8_wk  = (long)HID * CDIM / 8;
  const long c0 = n8_enc;
  const long c1 = c0 + n8_wq;
  const long c2 = c1 + n8_wk;
  const long c3 = c2 + n8_wk;
  const long c4 = c3 + n8_wq;
  cvt_multi<<<2048, 256, 0, stream>>>(enc, enc_h, c0, Wq, wq_h, c1,
                                      Wk, wk_h, c2, Wv, wv_h, c3,
                                      Wo, wo_h, c4);

  // ---- K and V projections in one launch ----
  gemm_kv<<<dim3(20, 10), 256, 0, stream>>>(enc_h, wk_h, wv_h, k_h, v_h,
                                            MKV, HID, CDIM);

  // ---- Q projection with fused f32->f16 A path ----
  const int grid_big = (MQ / 256) * (HID / 256);
  gemm_a32<<<dim3(grid_big), dim3(512), 131072, stream>>>(
      hs, wq_h, q_h, MQ, HID, HID);

  const float scale = 1.0f / sqrtf(160.0f);
  attn_fused<<<dim3(16, 8, 16), 256, 0, stream>>>(q_h, k_h, v_h, attn_h, scale);

  // ---- output projection (+bias, f32 out) ----
  gemm_8ph<0, 1><<<dim3(grid_big), dim3(512), 131072, stream>>>(
      attn_h, wo_h, out, bo, MQ, HID, HID);
}